// Round 1
// baseline (265.157 us; speedup 1.0000x reference)
//
#include <hip/hip_runtime.h>

// Problem constants (from reference)
#define B_ROWS 32768
#define S_SAMP 16
#define NRELS  238
#define DIM    256

typedef __attribute__((ext_vector_type(8))) short  short8;   // 8 x bf16 (4 VGPRs)
typedef __attribute__((ext_vector_type(4))) float  f32x4;    // MFMA accumulator

static __device__ __forceinline__ unsigned short f2bf(float f) {
    unsigned int u = __float_as_uint(f);
    u += 0x7FFFu + ((u >> 16) & 1u);   // round-to-nearest-even
    return (unsigned short)(u >> 16);
}
static __device__ __forceinline__ float bf2f(unsigned short u) {
    return __uint_as_float(((unsigned int)u) << 16);
}

// Kernel 1: convert W to bf16 (row-major [n][k] == B-frag layout) and
// transpose relation_weight [256,238] -> RWT [238,256] fp32 (contiguous gathers).
__global__ __launch_bounds__(256) void prep_kernel(const float* __restrict__ W,
                                                   const float* __restrict__ RW,
                                                   unsigned short* __restrict__ Wb,
                                                   float* __restrict__ RWT) {
    int i = blockIdx.x * 256 + threadIdx.x;
    if (i < DIM * DIM) Wb[i] = f2bf(W[i]);
    if (i < NRELS * DIM) {
        int r = i >> 8;      // relation id
        int d = i & 255;     // output dim
        RWT[i] = RW[d * NRELS + r];
    }
}

// Kernel 2: one wave per output row. 16 coalesced 1KB feature-row gathers +
// 16 relation-row gathers, fp32 mean, bf16 stores of A and RelA.
__global__ __launch_bounds__(256) void gather_kernel(const int* __restrict__ nbr,
                                                     const int* __restrict__ rels,
                                                     const float* __restrict__ feat,
                                                     const float* __restrict__ RWT,
                                                     unsigned short* __restrict__ A,
                                                     unsigned short* __restrict__ RelA) {
    const int lane = threadIdx.x & 63;
    const int row  = __builtin_amdgcn_readfirstlane(blockIdx.x * 4 + (threadIdx.x >> 6));
    const int* nb = nbr  + row * S_SAMP;   // wave-uniform -> s_load
    const int* rl = rels + row * S_SAMP;

    float a0 = 0.f, a1 = 0.f, a2 = 0.f, a3 = 0.f;
    float r0 = 0.f, r1 = 0.f, r2 = 0.f, r3 = 0.f;
#pragma unroll
    for (int s = 0; s < S_SAMP; ++s) {
        const int nid = nb[s];
        const int rid = rl[s];
        const float4 f = *(const float4*)(feat + (size_t)nid * DIM + lane * 4);
        const float4 g = *(const float4*)(RWT + rid * DIM + lane * 4);
        a0 += f.x; a1 += f.y; a2 += f.z; a3 += f.w;
        r0 += g.x; r1 += g.y; r2 += g.z; r3 += g.w;
    }
    const float sc = 1.0f / 16.0f;
    ushort4 pa, pr;
    pa.x = f2bf(a0 * sc); pa.y = f2bf(a1 * sc); pa.z = f2bf(a2 * sc); pa.w = f2bf(a3 * sc);
    pr.x = f2bf(r0 * sc); pr.y = f2bf(r1 * sc); pr.z = f2bf(r2 * sc); pr.w = f2bf(r3 * sc);
    *(ushort4*)(A    + (size_t)row * DIM + lane * 4) = pa;
    *(ushort4*)(RelA + (size_t)row * DIM + lane * 4) = pr;
}

// Kernel 3: C[64x256] tile per block (4 waves; each wave one 16-row m-tile,
// 16 n-tiles, K=256 in 8 steps of 32). A from LDS (row padded to 264 ushorts:
// 528B stride -> 4-bank rotation, free 2-way conflicts). B frags straight from
// global bf16 W (L1/L2-resident). Epilogue: + RelA, ReLU.
__global__ __launch_bounds__(256) void gemm_kernel(const unsigned short* __restrict__ A,
                                                   const unsigned short* __restrict__ Wb,
                                                   const unsigned short* __restrict__ RelA,
                                                   float* __restrict__ out) {
    __shared__ unsigned short Abuf[64][264];
    const int tid  = threadIdx.x;
    const int lane = tid & 63;
    const int wid  = tid >> 6;
    const int m0   = blockIdx.x * 64;

    // Stage the 64x256 bf16 A tile (32 KB contiguous) into LDS.
#pragma unroll
    for (int j = 0; j < 8; ++j) {
        int idx = (j * 256 + tid) * 8;          // ushort index in tile
        int r = idx >> 8;
        int c = idx & 255;
        uint4 v = *(const uint4*)(A + (size_t)m0 * DIM + idx);
        *(uint4*)&Abuf[r][c] = v;
    }
    __syncthreads();

    const int mrow = wid * 16 + (lane & 15);
    const int quad = lane >> 4;

    f32x4 acc[16];
#pragma unroll
    for (int n = 0; n < 16; ++n) acc[n] = (f32x4){0.f, 0.f, 0.f, 0.f};

#pragma unroll
    for (int kk = 0; kk < 8; ++kk) {
        short8 af = *(const short8*)&Abuf[mrow][kk * 32 + quad * 8];
#pragma unroll
        for (int n = 0; n < 16; ++n) {
            short8 bf = *(const short8*)(Wb + (size_t)(n * 16 + (lane & 15)) * DIM
                                            + kk * 32 + quad * 8);
            acc[n] = __builtin_amdgcn_mfma_f32_16x16x32_bf16(af, bf, acc[n], 0, 0, 0);
        }
    }

    // Epilogue: D[row=(lane>>4)*4+i][col=lane&15] per n-tile.
    const int col0  = lane & 15;
    const int rbase = m0 + wid * 16 + quad * 4;
#pragma unroll
    for (int n = 0; n < 16; ++n) {
        const int col = n * 16 + col0;
#pragma unroll
        for (int i = 0; i < 4; ++i) {
            const int r = rbase + i;
            float v = acc[n][i] + bf2f(RelA[(size_t)r * DIM + col]);
            out[(size_t)r * DIM + col] = v > 0.f ? v : 0.f;
        }
    }
}

extern "C" void kernel_launch(void* const* d_in, const int* in_sizes, int n_in,
                              void* d_out, int out_size, void* d_ws, size_t ws_size,
                              hipStream_t stream) {
    const int*   neighbors = (const int*)d_in[0];
    const int*   relations = (const int*)d_in[1];
    const float* features  = (const float*)d_in[2];
    const float* weight    = (const float*)d_in[3];
    const float* relw      = (const float*)d_in[4];
    float* out = (float*)d_out;

    char* ws = (char*)d_ws;
    // ws layout (bytes): Wb bf16 [256*256]  = 131072
    //                    RWT f32 [238*256]  = 243712
    //                    A  bf16 [32768*256] = 16777216
    //                    RelA bf16 [32768*256] = 16777216   (total ~34 MB)
    unsigned short* Wb   = (unsigned short*)ws;
    float*          RWT  = (float*)(ws + 131072);
    unsigned short* A    = (unsigned short*)(ws + 131072 + 243712);
    unsigned short* RelA = (unsigned short*)(ws + 131072 + 243712 + 16777216);

    prep_kernel<<<256, 256, 0, stream>>>(weight, relw, Wb, RWT);
    gather_kernel<<<B_ROWS / 4, 256, 0, stream>>>(neighbors, relations, features, RWT, A, RelA);
    gemm_kernel<<<B_ROWS / 64, 256, 0, stream>>>(A, Wb, RelA, out);
}